// Round 15
// baseline (58.453 us; speedup 1.0000x reference)
//
#include <hip/hip_runtime.h>
#include <hip/hip_bf16.h>

#define NUM_OPS 8
#define D 1024
#define B_ROWS 8192

typedef unsigned short ushort_t;
typedef __attribute__((ext_vector_type(8))) short bf16x8;
typedef __attribute__((ext_vector_type(4))) float f32x4;
typedef __attribute__((ext_vector_type(4))) float float4v;
typedef __attribute__((ext_vector_type(8))) unsigned short ushort8;

__device__ __forceinline__ unsigned short f2bf(float f) {
    union { float f; unsigned int u; } v; v.f = f;
    unsigned int u = v.u;
    unsigned int lsb = (u >> 16) & 1u;
    u += 0x7fffu + lsb;   // round-to-nearest-even
    return (unsigned short)(u >> 16);
}

// deterministic top-2 (matches jax top_k tie-breaking: earliest index wins)
__device__ __forceinline__ void top2(const float* __restrict__ logits, int& i0, int& i1) {
    float best = -__builtin_inff(); i0 = 0;
    for (int i = 0; i < NUM_OPS; ++i) { float v = logits[i]; if (v > best) { best = v; i0 = i; } }
    float best2 = -__builtin_inff(); i1 = 0;
    for (int i = 0; i < NUM_OPS; ++i) {
        if (i == i0) continue;
        float v = logits[i]; if (v > best2) { best2 = v; i1 = i; }
    }
}

// -------- x: f32 -> bf16, reordered into MFMA A-fragment layout (r8) --------
// Af byte addr of (r,u,f,lane): r*131072 + u*8192 + f*1024 + lane*16
__global__ void convert_frag_x(const float* __restrict__ x, ushort_t* __restrict__ Af) {
    __shared__ float t[64][65];
    const int b = blockIdx.x;            // r*16 + u
    const int r = b >> 4, u = b & 15;
    const int tid = threadIdx.x;

    const int row = tid >> 2, c0 = (tid & 3) * 16;
    const float* src = x + (size_t)(r * 64 + row) * D + u * 64 + c0;
    #pragma unroll
    for (int j = 0; j < 4; ++j) {
        float4v v = *(const float4v*)(src + j * 4);
        t[row][c0 + j * 4 + 0] = v[0];
        t[row][c0 + j * 4 + 1] = v[1];
        t[row][c0 + j * 4 + 2] = v[2];
        t[row][c0 + j * 4 + 3] = v[3];
    }
    __syncthreads();

    #pragma unroll
    for (int g2 = 0; g2 < 2; ++g2) {
        const int g = g2 * 256 + tid;
        const int f = g >> 6, lane = g & 63;     // f = kk*4 + m
        const int kk = f >> 2, m = f & 3;
        const int rr = m * 16 + (lane & 15);
        const int cc = kk * 32 + (lane >> 4) * 8;
        ushort8 o;
        #pragma unroll
        for (int j = 0; j < 8; ++j) o[j] = f2bf(t[rr][cc + j]);
        *(ushort8*)(Af + ((size_t)(r * 16 + u) * 8 + f) * 512 + lane * 8) = o;
    }
}

// ------- gather selected experts' W into MFMA B-fragment layout (r8) -------
// fi = (((e*32 + p)*16 + u)*2 + kk)*2 + n16 ; top-2 computed inline
__global__ void gather_frag_W(const float* __restrict__ Ws,
                              const float* __restrict__ logits,
                              ushort_t* __restrict__ Wf) {
    __shared__ float t[32][33];
    int s0, s1; top2(logits, s0, s1);
    const int b  = blockIdx.x;              // ((e*32 + kt)*32 + nt)
    const int nt = b & 31, kt = (b >> 5) & 31, e = b >> 10;
    const int td = kt * 32, te = nt * 32;
    const int tx = threadIdx.x & 31, ty = threadIdx.x >> 5;
    const float* W = Ws + (size_t)(e ? s1 : s0) * D * D;
    #pragma unroll
    for (int r = 0; r < 4; ++r)
        t[ty + 8 * r][tx] = W[(size_t)(td + ty + 8 * r) * D + te + tx];
    __syncthreads();
    const int vid = threadIdx.x;
    if (vid < 128) {
        const int n_l = vid & 31, kg = vid >> 5;
        const int n = te + n_l, k0 = td + kg * 8;
        const int u = k0 >> 6, kk = (k0 >> 5) & 1, lq = (k0 >> 3) & 3;
        const int p = n >> 5, n16 = (n >> 4) & 1, l15 = n & 15;
        const int lane = lq * 16 + l15;
        const int fi = (((e * 32 + p) * 16 + u) * 2 + kk) * 2 + n16;
        ushort8 o;
        #pragma unroll
        for (int j = 0; j < 8; ++j) o[j] = f2bf(t[kg * 8 + j][n_l]);
        *(ushort8*)(Wf + (size_t)fi * 512 + lane * 8) = o;
    }
}

#define SB()    __builtin_amdgcn_sched_barrier(0)
#define PRIO1() __builtin_amdgcn_s_setprio(1)
#define PRIO0() __builtin_amdgcn_s_setprio(0)
#define VMW(N)  do { asm volatile("s_waitcnt vmcnt(" #N ")" ::: "memory"); SB(); } while (0)

// inline-asm load: compiler cannot re-serialize or auto-waitcnt these.
#define GLD(dst, off, base, imm)                                               \
    asm volatile("global_load_dwordx4 %0, %1, %2 offset:" #imm                 \
                 : "=v"(dst) : "v"(off), "s"(base) : "memory")

// issue one K-tile's 16 fragment loads (A: 8, B: 8) into named set P
#define ISSUE(P, u)                                                            \
    do {                                                                       \
        unsigned vA  = aoff + (unsigned)(u) * 8192u;                           \
        unsigned vA2 = vA + 4096u;                                             \
        unsigned vB  = boff + (unsigned)(u) * 4096u;                           \
        unsigned vB2 = vB + 2097152u;                                          \
        GLD(P##a0, vA,  Af, 0);    GLD(P##a1, vA,  Af, 1024);                  \
        GLD(P##a2, vA,  Af, 2048); GLD(P##a3, vA,  Af, 3072);                  \
        GLD(P##a4, vA2, Af, 0);    GLD(P##a5, vA2, Af, 1024);                  \
        GLD(P##a6, vA2, Af, 2048); GLD(P##a7, vA2, Af, 3072);                  \
        GLD(P##b0, vB,  Wf, 0);    GLD(P##b1, vB,  Wf, 1024);                  \
        GLD(P##b2, vB,  Wf, 2048); GLD(P##b3, vB,  Wf, 3072);                  \
        GLD(P##b4, vB2, Wf, 0);    GLD(P##b5, vB2, Wf, 1024);                  \
        GLD(P##b6, vB2, Wf, 2048); GLD(P##b7, vB2, Wf, 3072);                  \
    } while (0)

#define MF(a, b, c) __builtin_amdgcn_mfma_f32_16x16x32_bf16(a, b, c, 0, 0, 0)
#define Q(P, A, B, E, M, N) acc[E][M][N] = MF(P##A, P##B, acc[E][M][N])

// 32 MFMA on set P. a index = kk*4+m ; b index = e*4 + kk*2 + n16
#define MFMA_SET(P)                                                            \
    do {                                                                       \
        PRIO1();                                                               \
        Q(P,a0,b0,0,0,0); Q(P,a0,b1,0,0,1); Q(P,a0,b4,1,0,0); Q(P,a0,b5,1,0,1);\
        Q(P,a1,b0,0,1,0); Q(P,a1,b1,0,1,1); Q(P,a1,b4,1,1,0); Q(P,a1,b5,1,1,1);\
        Q(P,a2,b0,0,2,0); Q(P,a2,b1,0,2,1); Q(P,a2,b4,1,2,0); Q(P,a2,b5,1,2,1);\
        Q(P,a3,b0,0,3,0); Q(P,a3,b1,0,3,1); Q(P,a3,b4,1,3,0); Q(P,a3,b5,1,3,1);\
        Q(P,a4,b2,0,0,0); Q(P,a4,b3,0,0,1); Q(P,a4,b6,1,0,0); Q(P,a4,b7,1,0,1);\
        Q(P,a5,b2,0,1,0); Q(P,a5,b3,0,1,1); Q(P,a5,b6,1,1,0); Q(P,a5,b7,1,1,1);\
        Q(P,a6,b2,0,2,0); Q(P,a6,b3,0,2,1); Q(P,a6,b6,1,2,0); Q(P,a6,b7,1,2,1);\
        Q(P,a7,b2,0,3,0); Q(P,a7,b3,0,3,1); Q(P,a7,b6,1,3,0); Q(P,a7,b7,1,3,1);\
        PRIO0();                                                               \
    } while (0)

// ---------------- fused dual-expert GEMM: asm-forced 2-deep pipeline --------
// r8 base (fastest measured GEMM, 45.3us). ONE structural change: the 4
// waves of a block now share the SAME A row-block (1r x 4p instead of
// 2r x 2p) -> A-frag loads are L1-broadcast across waves, cutting per-wave
// L2 traffic from 16KB to ~10KB per tile (r8 ran at ~68% of the L2
// contention knee; this moves it well under).
__global__ __launch_bounds__(256, 2)
void gemm_frag(const ushort_t* __restrict__ Af, const ushort_t* __restrict__ Wf,
               const float* __restrict__ bs, const float* __restrict__ logits,
               float* __restrict__ out) {
    const int tid  = threadIdx.x;
    const int wv   = tid >> 6;
    const int lane = tid & 63;
    const int l15  = lane & 15, lq = lane >> 4;

    // all 4 waves: same row-block r, adjacent 32-col panels p
    const int r = blockIdx.x & 127;                    // 0..127 row-block
    const int p = (blockIdx.x >> 7) * 4 + wv;          // 0..31 col-panel

    const unsigned aoff = (unsigned)r * 131072u + (unsigned)lane * 16u;
    const unsigned boff = (unsigned)p * 65536u  + (unsigned)lane * 16u;

    f32x4 acc[2][4][2] = {};

    bf16x8 Xa0, Xa1, Xa2, Xa3, Xa4, Xa5, Xa6, Xa7;
    bf16x8 Xb0, Xb1, Xb2, Xb3, Xb4, Xb5, Xb6, Xb7;
    bf16x8 Ya0, Ya1, Ya2, Ya3, Ya4, Ya5, Ya6, Ya7;
    bf16x8 Yb0, Yb1, Yb2, Yb3, Yb4, Yb5, Yb6, Yb7;

    ISSUE(X, 0); SB();
    ISSUE(Y, 1); SB();

    #pragma unroll 1
    for (int u = 0; u < 14; u += 2) {
        VMW(16);              // X (tile u) landed; Y still in flight
        MFMA_SET(X); SB();
        ISSUE(X, u + 2); SB();
        VMW(16);              // Y (tile u+1) landed; new X in flight
        MFMA_SET(Y); SB();
        ISSUE(Y, u + 3); SB();
    }
    VMW(16);                  // tile 14
    MFMA_SET(X); SB();
    VMW(0);                   // tile 15
    MFMA_SET(Y); SB();

    // ---- epilogue: per-expert bias + relu, sum, store f32
    int i0, i1; top2(logits, i0, i1);
    #pragma unroll
    for (int n16 = 0; n16 < 2; ++n16) {
        const int col = p * 32 + n16 * 16 + l15;
        const float b0 = bs[i0 * D + col];
        const float b1 = bs[i1 * D + col];
        #pragma unroll
        for (int m = 0; m < 4; ++m) {
            const int rbase = r * 64 + m * 16 + lq * 4;
            #pragma unroll
            for (int i = 0; i < 4; ++i) {
                float v0 = acc[0][m][n16][i] + b0; v0 = v0 > 0.f ? v0 : 0.f;
                float v1 = acc[1][m][n16][i] + b1; v1 = v1 > 0.f ? v1 : 0.f;
                out[(size_t)(rbase + i) * D + col] = v0 + v1;
            }
        }
    }
}

extern "C" void kernel_launch(void* const* d_in, const int* in_sizes, int n_in,
                              void* d_out, int out_size, void* d_ws, size_t ws_size,
                              hipStream_t stream) {
    const float* x      = (const float*)d_in[0];
    const float* logits = (const float*)d_in[1];
    const float* Ws     = (const float*)d_in[2];
    const float* bs     = (const float*)d_in[3];
    float* out = (float*)d_out;

    char* ws = (char*)d_ws;
    ushort_t* Af = (ushort_t*)ws;                                    // 16 MB
    ushort_t* Wf = (ushort_t*)(ws + (size_t)B_ROWS * D * 2);         //  4 MB

    convert_frag_x<<<128 * 16, 256, 0, stream>>>(x, Af);
    gather_frag_W<<<2 * 32 * 32, 256, 0, stream>>>(Ws, logits, Wf);

    gemm_frag<<<1024, 256, 0, stream>>>(Af, Wf, bs, logits, out);
}

// Round 16
// 55.806 us; speedup vs baseline: 1.0474x; 1.0474x over previous
//
#include <hip/hip_runtime.h>
#include <hip/hip_bf16.h>

#define NUM_OPS 8
#define D 1024
#define B_ROWS 8192

typedef unsigned short ushort_t;
typedef __attribute__((ext_vector_type(8))) short bf16x8;
typedef __attribute__((ext_vector_type(4))) float f32x4;
typedef __attribute__((ext_vector_type(4))) float float4v;
typedef __attribute__((ext_vector_type(8))) unsigned short ushort8;

__device__ __forceinline__ unsigned short f2bf(float f) {
    union { float f; unsigned int u; } v; v.f = f;
    unsigned int u = v.u;
    unsigned int lsb = (u >> 16) & 1u;
    u += 0x7fffu + lsb;   // round-to-nearest-even
    return (unsigned short)(u >> 16);
}

// deterministic top-2 (matches jax top_k tie-breaking: earliest index wins)
__device__ __forceinline__ void top2(const float* __restrict__ logits, int& i0, int& i1) {
    float best = -__builtin_inff(); i0 = 0;
    for (int i = 0; i < NUM_OPS; ++i) { float v = logits[i]; if (v > best) { best = v; i0 = i; } }
    float best2 = -__builtin_inff(); i1 = 0;
    for (int i = 0; i < NUM_OPS; ++i) {
        if (i == i0) continue;
        float v = logits[i]; if (v > best2) { best2 = v; i1 = i; }
    }
}

// -------- x: f32 -> bf16, reordered into MFMA A-fragment layout (r8) --------
// Af byte addr of (r,u,f,lane): r*131072 + u*8192 + f*1024 + lane*16
__global__ void convert_frag_x(const float* __restrict__ x, ushort_t* __restrict__ Af) {
    __shared__ float t[64][65];
    const int b = blockIdx.x;            // r*16 + u
    const int r = b >> 4, u = b & 15;
    const int tid = threadIdx.x;

    const int row = tid >> 2, c0 = (tid & 3) * 16;
    const float* src = x + (size_t)(r * 64 + row) * D + u * 64 + c0;
    #pragma unroll
    for (int j = 0; j < 4; ++j) {
        float4v v = *(const float4v*)(src + j * 4);
        t[row][c0 + j * 4 + 0] = v[0];
        t[row][c0 + j * 4 + 1] = v[1];
        t[row][c0 + j * 4 + 2] = v[2];
        t[row][c0 + j * 4 + 3] = v[3];
    }
    __syncthreads();

    #pragma unroll
    for (int g2 = 0; g2 < 2; ++g2) {
        const int g = g2 * 256 + tid;
        const int f = g >> 6, lane = g & 63;     // f = kk*4 + m
        const int kk = f >> 2, m = f & 3;
        const int rr = m * 16 + (lane & 15);
        const int cc = kk * 32 + (lane >> 4) * 8;
        ushort8 o;
        #pragma unroll
        for (int j = 0; j < 8; ++j) o[j] = f2bf(t[rr][cc + j]);
        *(ushort8*)(Af + ((size_t)(r * 16 + u) * 8 + f) * 512 + lane * 8) = o;
    }
}

// ------- gather selected experts' W into MFMA B-fragment layout (r8) -------
// fi = (((e*32 + p)*16 + u)*2 + kk)*2 + n16 ; top-2 computed inline
__global__ void gather_frag_W(const float* __restrict__ Ws,
                              const float* __restrict__ logits,
                              ushort_t* __restrict__ Wf) {
    __shared__ float t[32][33];
    int s0, s1; top2(logits, s0, s1);
    const int b  = blockIdx.x;              // ((e*32 + kt)*32 + nt)
    const int nt = b & 31, kt = (b >> 5) & 31, e = b >> 10;
    const int td = kt * 32, te = nt * 32;
    const int tx = threadIdx.x & 31, ty = threadIdx.x >> 5;
    const float* W = Ws + (size_t)(e ? s1 : s0) * D * D;
    #pragma unroll
    for (int r = 0; r < 4; ++r)
        t[ty + 8 * r][tx] = W[(size_t)(td + ty + 8 * r) * D + te + tx];
    __syncthreads();
    const int vid = threadIdx.x;
    if (vid < 128) {
        const int n_l = vid & 31, kg = vid >> 5;
        const int n = te + n_l, k0 = td + kg * 8;
        const int u = k0 >> 6, kk = (k0 >> 5) & 1, lq = (k0 >> 3) & 3;
        const int p = n >> 5, n16 = (n >> 4) & 1, l15 = n & 15;
        const int lane = lq * 16 + l15;
        const int fi = (((e * 32 + p) * 16 + u) * 2 + kk) * 2 + n16;
        ushort8 o;
        #pragma unroll
        for (int j = 0; j < 8; ++j) o[j] = f2bf(t[kg * 8 + j][n_l]);
        *(ushort8*)(Wf + (size_t)fi * 512 + lane * 8) = o;
    }
}

#define SB()    __builtin_amdgcn_sched_barrier(0)
#define PRIO1() __builtin_amdgcn_s_setprio(1)
#define PRIO0() __builtin_amdgcn_s_setprio(0)
#define VMW(N)  do { asm volatile("s_waitcnt vmcnt(" #N ")" ::: "memory"); SB(); } while (0)

// inline-asm load: compiler cannot re-serialize or auto-waitcnt these.
#define GLD(dst, off, base, imm)                                               \
    asm volatile("global_load_dwordx4 %0, %1, %2 offset:" #imm                 \
                 : "=v"(dst) : "v"(off), "s"(base) : "memory")

// issue one K-tile's 16 fragment loads (A: 8, B: 8) into named set P
#define ISSUE(P, u)                                                            \
    do {                                                                       \
        unsigned vA  = aoff + (unsigned)(u) * 8192u;                           \
        unsigned vA2 = vA + 4096u;                                             \
        unsigned vB  = boff + (unsigned)(u) * 4096u;                           \
        unsigned vB2 = vB + 2097152u;                                          \
        GLD(P##a0, vA,  Af, 0);    GLD(P##a1, vA,  Af, 1024);                  \
        GLD(P##a2, vA,  Af, 2048); GLD(P##a3, vA,  Af, 3072);                  \
        GLD(P##a4, vA2, Af, 0);    GLD(P##a5, vA2, Af, 1024);                  \
        GLD(P##a6, vA2, Af, 2048); GLD(P##a7, vA2, Af, 3072);                  \
        GLD(P##b0, vB,  Wf, 0);    GLD(P##b1, vB,  Wf, 1024);                  \
        GLD(P##b2, vB,  Wf, 2048); GLD(P##b3, vB,  Wf, 3072);                  \
        GLD(P##b4, vB2, Wf, 0);    GLD(P##b5, vB2, Wf, 1024);                  \
        GLD(P##b6, vB2, Wf, 2048); GLD(P##b7, vB2, Wf, 3072);                  \
    } while (0)

#define MF(a, b, c) __builtin_amdgcn_mfma_f32_16x16x32_bf16(a, b, c, 0, 0, 0)
#define Q(P, A, B, E, M, N) acc[E][M][N] = MF(P##A, P##B, acc[E][M][N])

// 32 MFMA on set P. a index = kk*4+m ; b index = e*4 + kk*2 + n16
#define MFMA_SET(P)                                                            \
    do {                                                                       \
        PRIO1();                                                               \
        Q(P,a0,b0,0,0,0); Q(P,a0,b1,0,0,1); Q(P,a0,b4,1,0,0); Q(P,a0,b5,1,0,1);\
        Q(P,a1,b0,0,1,0); Q(P,a1,b1,0,1,1); Q(P,a1,b4,1,1,0); Q(P,a1,b5,1,1,1);\
        Q(P,a2,b0,0,2,0); Q(P,a2,b1,0,2,1); Q(P,a2,b4,1,2,0); Q(P,a2,b5,1,2,1);\
        Q(P,a3,b0,0,3,0); Q(P,a3,b1,0,3,1); Q(P,a3,b4,1,3,0); Q(P,a3,b5,1,3,1);\
        Q(P,a4,b2,0,0,0); Q(P,a4,b3,0,0,1); Q(P,a4,b6,1,0,0); Q(P,a4,b7,1,0,1);\
        Q(P,a5,b2,0,1,0); Q(P,a5,b3,0,1,1); Q(P,a5,b6,1,1,0); Q(P,a5,b7,1,1,1);\
        Q(P,a6,b2,0,2,0); Q(P,a6,b3,0,2,1); Q(P,a6,b6,1,2,0); Q(P,a6,b7,1,2,1);\
        Q(P,a7,b2,0,3,0); Q(P,a7,b3,0,3,1); Q(P,a7,b6,1,3,0); Q(P,a7,b7,1,3,1);\
        PRIO0();                                                               \
    } while (0)

// ---------------- fused dual-expert GEMM: asm-forced 2-deep pipeline --------
// r8 base (fastest GEMM, 45.3us), waves 2r x 2p (r8's proven sharing).
// ONE change: XCD-confined A working set. XCD x (= bid%8) exclusively owns
// row-blocks r in [16x, 16x+16) -> its Af slice is 2MB (L2-resident, fetched
// from HBM once chip-wide); p-pairs swept slowly (B window 128KB, L2-hot).
// The depth-2 pipeline's ~220-cyc cover beats L2 latency but not L3/HBM;
// this mapping converts A-misses into L2 hits.
__global__ __launch_bounds__(256, 2)
void gemm_frag(const ushort_t* __restrict__ Af, const ushort_t* __restrict__ Wf,
               const float* __restrict__ bs, const float* __restrict__ logits,
               float* __restrict__ out) {
    const int tid  = threadIdx.x;
    const int wv   = tid >> 6;
    const int lane = tid & 63;
    const int l15  = lane & 15, lq = lane >> 4;

    const int bid = blockIdx.x;
    const int rp  = (bid & 7) * 8 + ((bid >> 3) & 7);  // row-pair, XCD-confined
    const int r   = rp * 2 + (wv & 1);                 // 0..127 row-block
    const int p   = (bid >> 6) * 2 + (wv >> 1);        // 0..31 col-panel

    const unsigned aoff = (unsigned)r * 131072u + (unsigned)lane * 16u;
    const unsigned boff = (unsigned)p * 65536u  + (unsigned)lane * 16u;

    f32x4 acc[2][4][2] = {};

    bf16x8 Xa0, Xa1, Xa2, Xa3, Xa4, Xa5, Xa6, Xa7;
    bf16x8 Xb0, Xb1, Xb2, Xb3, Xb4, Xb5, Xb6, Xb7;
    bf16x8 Ya0, Ya1, Ya2, Ya3, Ya4, Ya5, Ya6, Ya7;
    bf16x8 Yb0, Yb1, Yb2, Yb3, Yb4, Yb5, Yb6, Yb7;

    ISSUE(X, 0); SB();
    ISSUE(Y, 1); SB();

    #pragma unroll 1
    for (int u = 0; u < 14; u += 2) {
        VMW(16);              // X (tile u) landed; Y still in flight
        MFMA_SET(X); SB();
        ISSUE(X, u + 2); SB();
        VMW(16);              // Y (tile u+1) landed; new X in flight
        MFMA_SET(Y); SB();
        ISSUE(Y, u + 3); SB();
    }
    VMW(16);                  // tile 14
    MFMA_SET(X); SB();
    VMW(0);                   // tile 15
    MFMA_SET(Y); SB();

    // ---- epilogue: per-expert bias + relu, sum, store f32
    int i0, i1; top2(logits, i0, i1);
    #pragma unroll
    for (int n16 = 0; n16 < 2; ++n16) {
        const int col = p * 32 + n16 * 16 + l15;
        const float b0 = bs[i0 * D + col];
        const float b1 = bs[i1 * D + col];
        #pragma unroll
        for (int m = 0; m < 4; ++m) {
            const int rbase = r * 64 + m * 16 + lq * 4;
            #pragma unroll
            for (int i = 0; i < 4; ++i) {
                float v0 = acc[0][m][n16][i] + b0; v0 = v0 > 0.f ? v0 : 0.f;
                float v1 = acc[1][m][n16][i] + b1; v1 = v1 > 0.f ? v1 : 0.f;
                out[(size_t)(rbase + i) * D + col] = v0 + v1;
            }
        }
    }
}

extern "C" void kernel_launch(void* const* d_in, const int* in_sizes, int n_in,
                              void* d_out, int out_size, void* d_ws, size_t ws_size,
                              hipStream_t stream) {
    const float* x      = (const float*)d_in[0];
    const float* logits = (const float*)d_in[1];
    const float* Ws     = (const float*)d_in[2];
    const float* bs     = (const float*)d_in[3];
    float* out = (float*)d_out;

    char* ws = (char*)d_ws;
    ushort_t* Af = (ushort_t*)ws;                                    // 16 MB
    ushort_t* Wf = (ushort_t*)(ws + (size_t)B_ROWS * D * 2);         //  4 MB

    convert_frag_x<<<128 * 16, 256, 0, stream>>>(x, Af);
    gather_frag_W<<<2 * 32 * 32, 256, 0, stream>>>(Ws, logits, Wf);

    gemm_frag<<<1024, 256, 0, stream>>>(Af, Wf, bs, logits, out);
}

// Round 17
// 54.444 us; speedup vs baseline: 1.0736x; 1.0250x over previous
//
#include <hip/hip_runtime.h>
#include <hip/hip_bf16.h>

#define NUM_OPS 8
#define D 1024
#define B_ROWS 8192

typedef unsigned short ushort_t;
typedef __attribute__((ext_vector_type(8))) short bf16x8;
typedef __attribute__((ext_vector_type(4))) float f32x4;
typedef __attribute__((ext_vector_type(4))) float float4v;
typedef __attribute__((ext_vector_type(8))) unsigned short ushort8;

__device__ __forceinline__ unsigned short f2bf(float f) {
    union { float f; unsigned int u; } v; v.f = f;
    unsigned int u = v.u;
    unsigned int lsb = (u >> 16) & 1u;
    u += 0x7fffu + lsb;   // round-to-nearest-even
    return (unsigned short)(u >> 16);
}

// deterministic top-2 (matches jax top_k tie-breaking: earliest index wins)
__device__ __forceinline__ void top2(const float* __restrict__ logits, int& i0, int& i1) {
    float best = -__builtin_inff(); i0 = 0;
    for (int i = 0; i < NUM_OPS; ++i) { float v = logits[i]; if (v > best) { best = v; i0 = i; } }
    float best2 = -__builtin_inff(); i1 = 0;
    for (int i = 0; i < NUM_OPS; ++i) {
        if (i == i0) continue;
        float v = logits[i]; if (v > best2) { best2 = v; i1 = i; }
    }
}

// -------- merged prep: x->Af fragments (blocks 0..2047), W->Wf (2048..4095) --
// Af byte addr of (r,u,f,lane): r*131072 + u*8192 + f*1024 + lane*16
// Wf: fi = (((e*32 + p)*16 + u)*2 + kk)*2 + n16 (r8-verified layouts)
__global__ void prep_kernel(const float* __restrict__ x,
                            const float* __restrict__ Ws,
                            const float* __restrict__ logits,
                            ushort_t* __restrict__ Af,
                            ushort_t* __restrict__ Wf) {
    __shared__ __align__(16) float smem[64 * 65];
    const int bid = blockIdx.x;
    const int tid = threadIdx.x;

    if (bid < 2048) {
        // ---- convert_frag_x body (r15-verified), t[row][col] = smem[row*65+col]
        const int b = bid;                   // r*16 + u
        const int r = b >> 4, u = b & 15;
        const int row = tid >> 2, c0 = (tid & 3) * 16;
        const float* src = x + (size_t)(r * 64 + row) * D + u * 64 + c0;
        #pragma unroll
        for (int j = 0; j < 4; ++j) {
            float4v v = *(const float4v*)(src + j * 4);
            smem[row * 65 + c0 + j * 4 + 0] = v[0];
            smem[row * 65 + c0 + j * 4 + 1] = v[1];
            smem[row * 65 + c0 + j * 4 + 2] = v[2];
            smem[row * 65 + c0 + j * 4 + 3] = v[3];
        }
        __syncthreads();
        #pragma unroll
        for (int g2 = 0; g2 < 2; ++g2) {
            const int g = g2 * 256 + tid;
            const int f = g >> 6, lane = g & 63;     // f = kk*4 + m
            const int kk = f >> 2, m = f & 3;
            const int rr = m * 16 + (lane & 15);
            const int cc = kk * 32 + (lane >> 4) * 8;
            ushort8 o;
            #pragma unroll
            for (int j = 0; j < 8; ++j) o[j] = f2bf(smem[rr * 65 + cc + j]);
            *(ushort8*)(Af + ((size_t)(r * 16 + u) * 8 + f) * 512 + lane * 8) = o;
        }
    } else {
        // ---- gather_frag_W body (r8-verified), t[a][b] = smem[a*33+b]
        int s0, s1; top2(logits, s0, s1);
        const int b  = bid - 2048;           // ((e*32 + kt)*32 + nt)
        const int nt = b & 31, kt = (b >> 5) & 31, e = b >> 10;
        const int td = kt * 32, te = nt * 32;
        const int tx = tid & 31, ty = tid >> 5;
        const float* W = Ws + (size_t)(e ? s1 : s0) * D * D;
        #pragma unroll
        for (int r = 0; r < 4; ++r)
            smem[(ty + 8 * r) * 33 + tx] = W[(size_t)(td + ty + 8 * r) * D + te + tx];
        __syncthreads();
        if (tid < 128) {
            const int n_l = tid & 31, kg = tid >> 5;
            const int n = te + n_l, k0 = td + kg * 8;
            const int u = k0 >> 6, kk = (k0 >> 5) & 1, lq = (k0 >> 3) & 3;
            const int p = n >> 5, n16 = (n >> 4) & 1, l15 = n & 15;
            const int lane = lq * 16 + l15;
            const int fi = (((e * 32 + p) * 16 + u) * 2 + kk) * 2 + n16;
            ushort8 o;
            #pragma unroll
            for (int j = 0; j < 8; ++j) o[j] = f2bf(smem[(kg * 8 + j) * 33 + n_l]);
            *(ushort8*)(Wf + (size_t)fi * 512 + lane * 8) = o;
        }
    }
}

#define SB()    __builtin_amdgcn_sched_barrier(0)
#define PRIO1() __builtin_amdgcn_s_setprio(1)
#define PRIO0() __builtin_amdgcn_s_setprio(0)
#define VMW(N)  do { asm volatile("s_waitcnt vmcnt(" #N ")" ::: "memory"); SB(); } while (0)

// inline-asm load: compiler cannot re-serialize or auto-waitcnt these.
#define GLD(dst, off, base, imm)                                               \
    asm volatile("global_load_dwordx4 %0, %1, %2 offset:" #imm                 \
                 : "=v"(dst) : "v"(off), "s"(base) : "memory")

// half-set H0: kk=0 fragments {a0..a3, b0,b1 (e0), b4,b5 (e1)}
#define ISSUE_H0(P, u)                                                         \
    do {                                                                       \
        unsigned vA = aoff + (unsigned)(u) * 8192u;                            \
        unsigned vB = boff + (unsigned)(u) * 4096u;                            \
        unsigned vB2 = vB + 2097152u;                                          \
        GLD(P##a0, vA, Af, 0);    GLD(P##a1, vA, Af, 1024);                    \
        GLD(P##a2, vA, Af, 2048); GLD(P##a3, vA, Af, 3072);                    \
        GLD(P##b0, vB, Wf, 0);    GLD(P##b1, vB, Wf, 1024);                    \
        GLD(P##b4, vB2, Wf, 0);   GLD(P##b5, vB2, Wf, 1024);                   \
    } while (0)

// half-set H1: kk=1 fragments {a4..a7, b2,b3 (e0), b6,b7 (e1)}
#define ISSUE_H1(P, u)                                                         \
    do {                                                                       \
        unsigned vA2 = aoff + (unsigned)(u) * 8192u + 4096u;                   \
        unsigned vB = boff + (unsigned)(u) * 4096u;                            \
        unsigned vB2 = vB + 2097152u;                                          \
        GLD(P##a4, vA2, Af, 0);    GLD(P##a5, vA2, Af, 1024);                  \
        GLD(P##a6, vA2, Af, 2048); GLD(P##a7, vA2, Af, 3072);                  \
        GLD(P##b2, vB, Wf, 2048);  GLD(P##b3, vB, Wf, 3072);                   \
        GLD(P##b6, vB2, Wf, 2048); GLD(P##b7, vB2, Wf, 3072);                  \
    } while (0)

#define MF(a, b, c) __builtin_amdgcn_mfma_f32_16x16x32_bf16(a, b, c, 0, 0, 0)
#define Q(P, A, B, E, M, N) acc[E][M][N] = MF(P##A, P##B, acc[E][M][N])

// 16 MFMA on half-set H0 of P (kk=0)
#define MFMA_H0(P)                                                             \
    do {                                                                       \
        PRIO1();                                                               \
        Q(P,a0,b0,0,0,0); Q(P,a0,b1,0,0,1); Q(P,a0,b4,1,0,0); Q(P,a0,b5,1,0,1);\
        Q(P,a1,b0,0,1,0); Q(P,a1,b1,0,1,1); Q(P,a1,b4,1,1,0); Q(P,a1,b5,1,1,1);\
        Q(P,a2,b0,0,2,0); Q(P,a2,b1,0,2,1); Q(P,a2,b4,1,2,0); Q(P,a2,b5,1,2,1);\
        Q(P,a3,b0,0,3,0); Q(P,a3,b1,0,3,1); Q(P,a3,b4,1,3,0); Q(P,a3,b5,1,3,1);\
        PRIO0();                                                               \
    } while (0)

// 16 MFMA on half-set H1 of P (kk=1)
#define MFMA_H1(P)                                                             \
    do {                                                                       \
        PRIO1();                                                               \
        Q(P,a4,b2,0,0,0); Q(P,a4,b3,0,0,1); Q(P,a4,b6,1,0,0); Q(P,a4,b7,1,0,1);\
        Q(P,a5,b2,0,1,0); Q(P,a5,b3,0,1,1); Q(P,a5,b6,1,1,0); Q(P,a5,b7,1,1,1);\
        Q(P,a6,b2,0,2,0); Q(P,a6,b3,0,2,1); Q(P,a6,b6,1,2,0); Q(P,a6,b7,1,2,1);\
        Q(P,a7,b2,0,3,0); Q(P,a7,b3,0,3,1); Q(P,a7,b6,1,3,0); Q(P,a7,b7,1,3,1);\
        PRIO0();                                                               \
    } while (0)

// ---------------- fused dual-expert GEMM: half-set smoothed pipeline --------
// r8 base. ONE change: the per-tile {VMW(16); 32 MFMA; burst 16 loads}
// sawtooth becomes 4x {VMW(24); 16 MFMA; issue 8 loads} -- outstanding
// pinned at 24-32 (delivery never drains), each half-set gets ~1.5 tiles
// (~660 cyc) of flight. Same registers, same addresses, same MFMA order.
__global__ __launch_bounds__(256, 2)
void gemm_frag(const ushort_t* __restrict__ Af, const ushort_t* __restrict__ Wf,
               const float* __restrict__ bs, const float* __restrict__ logits,
               float* __restrict__ out) {
    const int tid  = threadIdx.x;
    const int wv   = tid >> 6;
    const int lane = tid & 63;
    const int l15  = lane & 15, lq = lane >> 4;

    const int r = (blockIdx.x & 63) * 2 + (wv & 1);    // 0..127 row-block
    const int p = (blockIdx.x >> 6) * 2 + (wv >> 1);   // 0..31 col-panel

    const unsigned aoff = (unsigned)r * 131072u + (unsigned)lane * 16u;
    const unsigned boff = (unsigned)p * 65536u  + (unsigned)lane * 16u;

    f32x4 acc[2][4][2] = {};

    bf16x8 Xa0, Xa1, Xa2, Xa3, Xa4, Xa5, Xa6, Xa7;
    bf16x8 Xb0, Xb1, Xb2, Xb3, Xb4, Xb5, Xb6, Xb7;
    bf16x8 Ya0, Ya1, Ya2, Ya3, Ya4, Ya5, Ya6, Ya7;
    bf16x8 Yb0, Yb1, Yb2, Yb3, Yb4, Yb5, Yb6, Yb7;

    // prologue: 32 loads in flight (X(0).H0, X(0).H1, Y(1).H0, Y(1).H1)
    ISSUE_H0(X, 0); SB();
    ISSUE_H1(X, 0); SB();
    ISSUE_H0(Y, 1); SB();
    ISSUE_H1(Y, 1); SB();

    #pragma unroll 1
    for (int u = 0; u < 14; u += 2) {
        VMW(24);                       // X.H0(u) landed
        MFMA_H0(X); SB();
        ISSUE_H0(X, u + 2); SB();
        VMW(24);                       // X.H1(u) landed
        MFMA_H1(X); SB();
        ISSUE_H1(X, u + 2); SB();
        VMW(24);                       // Y.H0(u+1) landed
        MFMA_H0(Y); SB();
        ISSUE_H0(Y, u + 3); SB();
        VMW(24);                       // Y.H1(u+1) landed
        MFMA_H1(Y); SB();
        ISSUE_H1(Y, u + 3); SB();
    }
    // tail: tiles 14 (X), 15 (Y); outstanding drains 32 -> 0
    VMW(24); MFMA_H0(X); SB();
    VMW(16); MFMA_H1(X); SB();
    VMW(8);  MFMA_H0(Y); SB();
    VMW(0);  MFMA_H1(Y); SB();

    // ---- epilogue: per-expert bias + relu, sum, store f32
    int i0, i1; top2(logits, i0, i1);
    #pragma unroll
    for (int n16 = 0; n16 < 2; ++n16) {
        const int col = p * 32 + n16 * 16 + l15;
        const float b0 = bs[i0 * D + col];
        const float b1 = bs[i1 * D + col];
        #pragma unroll
        for (int m = 0; m < 4; ++m) {
            const int rbase = r * 64 + m * 16 + lq * 4;
            #pragma unroll
            for (int i = 0; i < 4; ++i) {
                float v0 = acc[0][m][n16][i] + b0; v0 = v0 > 0.f ? v0 : 0.f;
                float v1 = acc[1][m][n16][i] + b1; v1 = v1 > 0.f ? v1 : 0.f;
                out[(size_t)(rbase + i) * D + col] = v0 + v1;
            }
        }
    }
}

extern "C" void kernel_launch(void* const* d_in, const int* in_sizes, int n_in,
                              void* d_out, int out_size, void* d_ws, size_t ws_size,
                              hipStream_t stream) {
    const float* x      = (const float*)d_in[0];
    const float* logits = (const float*)d_in[1];
    const float* Ws     = (const float*)d_in[2];
    const float* bs     = (const float*)d_in[3];
    float* out = (float*)d_out;

    char* ws = (char*)d_ws;
    ushort_t* Af = (ushort_t*)ws;                                    // 16 MB
    ushort_t* Wf = (ushort_t*)(ws + (size_t)B_ROWS * D * 2);         //  4 MB

    prep_kernel<<<4096, 256, 0, stream>>>(x, Ws, logits, Af, Wf);
    gemm_frag<<<1024, 256, 0, stream>>>(Af, Wf, bs, logits, out);
}

// Round 18
// 49.059 us; speedup vs baseline: 1.1915x; 1.1098x over previous
//
#include <hip/hip_runtime.h>
#include <hip/hip_bf16.h>

#define NUM_OPS 8
#define D 1024
#define B_ROWS 8192

typedef unsigned short ushort_t;
typedef __attribute__((ext_vector_type(8))) short bf16x8;
typedef __attribute__((ext_vector_type(4))) float f32x4;
typedef __attribute__((ext_vector_type(4))) float float4v;
typedef __attribute__((ext_vector_type(8))) unsigned short ushort8;

__device__ __forceinline__ unsigned short f2bf(float f) {
    union { float f; unsigned int u; } v; v.f = f;
    unsigned int u = v.u;
    unsigned int lsb = (u >> 16) & 1u;
    u += 0x7fffu + lsb;   // round-to-nearest-even
    return (unsigned short)(u >> 16);
}

__device__ __forceinline__ void load_lds16(const void* g, void* l) {
    __builtin_amdgcn_global_load_lds(
        (const __attribute__((address_space(1))) void*)g,
        (__attribute__((address_space(3))) void*)l,
        16, 0, 0);
}

// deterministic top-2 (matches jax top_k tie-breaking: earliest index wins)
__device__ __forceinline__ void top2(const float* __restrict__ logits, int& i0, int& i1) {
    float best = -__builtin_inff(); i0 = 0;
    for (int i = 0; i < NUM_OPS; ++i) { float v = logits[i]; if (v > best) { best = v; i0 = i; } }
    float best2 = -__builtin_inff(); i1 = 0;
    for (int i = 0; i < NUM_OPS; ++i) {
        if (i == i0) continue;
        float v = logits[i]; if (v > best2) { best2 = v; i1 = i; }
    }
}

// -------- merged prep: x->bf16 linear (blocks 0..4095), W gather-transpose --
__global__ void prep_kernel(const float* __restrict__ x,
                            const float* __restrict__ Ws,
                            const float* __restrict__ logits,
                            ushort_t* __restrict__ xbf,
                            ushort_t* __restrict__ Wt) {
    __shared__ float t[32][33];
    const int bid = blockIdx.x;
    const int tid = threadIdx.x;
    if (bid < 4096) {
        // convert_x (r9-verified)
        int i = (bid * 256 + tid) * 8;
        float4v v0 = *(const float4v*)(x + i);
        float4v v1 = *(const float4v*)(x + i + 4);
        ushort8 o;
        o[0] = f2bf(v0[0]); o[1] = f2bf(v0[1]); o[2] = f2bf(v0[2]); o[3] = f2bf(v0[3]);
        o[4] = f2bf(v1[0]); o[5] = f2bf(v1[1]); o[6] = f2bf(v1[2]); o[7] = f2bf(v1[3]);
        *(ushort8*)(xbf + i) = o;
    } else {
        // gather_transpose_W (r9-verified): Wt[e][n*D+k] = bf16(W_sel[k*D+n])
        int i0, i1; top2(logits, i0, i1);
        const int b  = bid - 4096;
        const int e    = b >> 10;
        const int tile = b & 1023;
        const int td = (tile >> 5) << 5;
        const int te = (tile & 31) << 5;
        const int tx = tid & 31, ty = tid >> 5;
        const float* W = Ws + (size_t)(e ? i1 : i0) * D * D;
        for (int r = 0; r < 4; ++r)
            t[ty + 8 * r][tx] = W[(size_t)(td + ty + 8 * r) * D + te + tx];
        __syncthreads();
        ushort_t* o = Wt + (size_t)e * D * D;
        for (int r = 0; r < 4; ++r)
            o[(size_t)(te + ty + 8 * r) * D + td + tx] = f2bf(t[tx][ty + 8 * r]);
    }
}

// -------- staging (r9-verified): linear LDS dest, inverse-swizzled source ---
// LDS row = 128B; byte (r*128+c') holds global col-byte (c' ^ ((r&7)<<4)).
__device__ __forceinline__ void stageA(const ushort_t* __restrict__ xbf, int brow,
                                       int u, ushort_t* dst, int tid) {
    #pragma unroll
    for (int q = 0; q < 4; ++q) {                       // 256 rows x 128B = 32KB
        const int c   = q * 512 + tid;
        const int rr  = c >> 3;
        const int gcb = ((c & 7) * 16) ^ ((rr & 7) << 4);
        load_lds16(xbf + (size_t)(brow + rr) * D + u * 64 + (gcb >> 1), dst + c * 8);
    }
}
__device__ __forceinline__ void stageB(const ushort_t* __restrict__ Wt, int bcol,
                                       int u, ushort_t* dst, int tid) {
    #pragma unroll
    for (int q = 0; q < 2; ++q) {                       // 2e x 64 rows x 128B = 16KB
        const int c   = q * 512 + tid;
        const int e   = c >> 9, cc = c & 511;
        const int n   = cc >> 3;
        const int gcb = ((cc & 7) * 16) ^ ((n & 7) << 4);
        load_lds16(Wt + (size_t)e * D * D + (size_t)(bcol + n) * D + u * 64 + (gcb >> 1),
                   dst + c * 8);
    }
}

#define SB()    __builtin_amdgcn_sched_barrier(0)
#define PRIO1() __builtin_amdgcn_s_setprio(1)
#define PRIO0() __builtin_amdgcn_s_setprio(0)
#define VMW(N)  do { asm volatile("s_waitcnt vmcnt(" #N ")" ::: "memory"); SB(); } while (0)
#define LGW(N)  do { asm volatile("s_waitcnt lgkmcnt(" #N ")" ::: "memory"); SB(); } while (0)
#define BAR()   do { __builtin_amdgcn_s_barrier(); SB(); } while (0)

// inline-asm LDS read: allocator cannot collapse these; regs stay live.
#define DSR(dst, addr, imm)                                                    \
    asm volatile("ds_read_b128 %0, %1 offset:" #imm : "=v"(dst) : "v"(addr))

// issue one tile's 16 fragment ds_reads into named set P from slots SA/SBB.
// A frag (kk,m): addr = SA + (rgrp*64+l15)*128 + x{kk}, imm m*2048
// B frag (e,kk,n16): addr = SBB + (cgrp*32+l15)*128 + x{kk}, imm e*8192+n16*2048
#define ISSUE_DS(P, SA, SBB)                                                   \
    do {                                                                       \
        unsigned aA0 = (unsigned)(size_t)(SA) + aro + x0;                      \
        unsigned aA1 = (unsigned)(size_t)(SA) + aro + x1;                      \
        unsigned aB0 = (unsigned)(size_t)(SBB) + bro + x0;                     \
        unsigned aB1 = (unsigned)(size_t)(SBB) + bro + x1;                     \
        DSR(P##a0, aA0, 0);    DSR(P##a1, aA0, 2048);                          \
        DSR(P##a2, aA0, 4096); DSR(P##a3, aA0, 6144);                          \
        DSR(P##a4, aA1, 0);    DSR(P##a5, aA1, 2048);                          \
        DSR(P##a6, aA1, 4096); DSR(P##a7, aA1, 6144);                          \
        DSR(P##b0, aB0, 0);    DSR(P##b1, aB0, 2048);                          \
        DSR(P##b4, aB0, 8192); DSR(P##b5, aB0, 10240);                         \
        DSR(P##b2, aB1, 0);    DSR(P##b3, aB1, 2048);                          \
        DSR(P##b6, aB1, 8192); DSR(P##b7, aB1, 10240);                         \
    } while (0)

#define MF(a, b, c) __builtin_amdgcn_mfma_f32_16x16x32_bf16(a, b, c, 0, 0, 0)
#define Q(P, A, B, E, M, N) acc[E][M][N] = MF(P##A, P##B, acc[E][M][N])

// 32 MFMA on set P. a index = kk*4+m ; b index = e*4 + kk*2 + n16 (r8-verified)
#define MFMA_SET(P)                                                            \
    do {                                                                       \
        PRIO1();                                                               \
        Q(P,a0,b0,0,0,0); Q(P,a0,b1,0,0,1); Q(P,a0,b4,1,0,0); Q(P,a0,b5,1,0,1);\
        Q(P,a1,b0,0,1,0); Q(P,a1,b1,0,1,1); Q(P,a1,b4,1,1,0); Q(P,a1,b5,1,1,1);\
        Q(P,a2,b0,0,2,0); Q(P,a2,b1,0,2,1); Q(P,a2,b4,1,2,0); Q(P,a2,b5,1,2,1);\
        Q(P,a3,b0,0,3,0); Q(P,a3,b1,0,3,1); Q(P,a3,b4,1,3,0); Q(P,a3,b5,1,3,1);\
        Q(P,a4,b2,0,0,0); Q(P,a4,b3,0,0,1); Q(P,a4,b6,1,0,0); Q(P,a4,b7,1,0,1);\
        Q(P,a5,b2,0,1,0); Q(P,a5,b3,0,1,1); Q(P,a5,b6,1,1,0); Q(P,a5,b7,1,1,1);\
        Q(P,a6,b2,0,2,0); Q(P,a6,b3,0,2,1); Q(P,a6,b6,1,2,0); Q(P,a6,b7,1,2,1);\
        Q(P,a7,b2,0,3,0); Q(P,a7,b3,0,3,1); Q(P,a7,b6,1,3,0); Q(P,a7,b7,1,3,1);\
        PRIO0();                                                               \
    } while (0)

// one K-tile u (steady state):
//   VMW(0): stage(u+1) complete (issued a full tile ago -> ~free)
//   BARRIER: slot[(u+1)%3] visible to all waves; also: every wave's reads of
//     slot[(u+2)%3]'s OLD content completed (its LGW last tile precedes this
//     barrier) -> stage(u+2) below is WAR-safe.
//   ISSUE_DS F(u+1) (16 asm ds_read, NOT waited -- fly under MFMA)
//   stage(u+2) (6 global_load_lds)
//   LGW(15): drains the 16 reads issued LAST tile (F(u)); ~1 of the new
//     16 also drains (lgkmcnt is 4-bit, max 15) -- negligible.
//   MFMA_SET(F(u))
#define TILE(SETN, SA, SBB, SU, DA, DB, SETC, DOSTG)                           \
    do {                                                                       \
        VMW(0);                                                                \
        BAR();                                                                 \
        ISSUE_DS(SETN, SA, SBB);                                               \
        if (DOSTG) { stageA(xbf, brow, (SU), DA, tid);                         \
                     stageB(Wt,  bcol, (SU), DB, tid); }                       \
        SB();                                                                  \
        LGW(15);                                                               \
        MFMA_SET(SETC);                                                        \
        SB();                                                                  \
    } while (0)

// -------- fused dual-expert GEMM: asm-forced LDS pipeline, ring-3 slots -----
// r9 geometry: 256r x 64c x 2e block, 8 waves (4r x 2c), BK=64, 144KB LDS.
// KEY: tile u+1's fragment ds_reads are inline-asm issued BEFORE MFMA(u) and
// waited with a literal counted lgkmcnt -- LDS-read (~1760 cyc/tile/CU)
// overlaps MFMA (~1240) instead of adding (r13's serialization, 3900 cyc).
__global__ __launch_bounds__(512, 2)
void gemm_dual(const ushort_t* __restrict__ xbf, const ushort_t* __restrict__ Wt,
               const float* __restrict__ bs, const float* __restrict__ logits,
               float* __restrict__ out) {
    __shared__ __align__(16) ushort_t As0[256 * 64], As1[256 * 64], As2[256 * 64];
    __shared__ __align__(16) ushort_t Bs0[2 * 64 * 64], Bs1[2 * 64 * 64], Bs2[2 * 64 * 64];

    const int tid  = threadIdx.x;
    const int wv   = tid >> 6;
    const int lane = tid & 63;
    const int rgrp = wv >> 1, cgrp = wv & 1;
    const int l15  = lane & 15, lq = lane >> 4;
    const int swz  = (l15 & 7) << 4;
    const int x0   = (lq * 16) ^ swz;
    const int x1   = (64 + lq * 16) ^ swz;
    const unsigned aro = (unsigned)((rgrp * 64 + l15) * 128);
    const unsigned bro = (unsigned)((cgrp * 32 + l15) * 128);

    const int bid  = blockIdx.x;
    const int brow = (bid & 31) * 256;
    const int bcol = (bid >> 5) * 64;

    f32x4 acc[2][4][2] = {};

    bf16x8 Xa0, Xa1, Xa2, Xa3, Xa4, Xa5, Xa6, Xa7;
    bf16x8 Xb0, Xb1, Xb2, Xb3, Xb4, Xb5, Xb6, Xb7;
    bf16x8 Ya0, Ya1, Ya2, Ya3, Ya4, Ya5, Ya6, Ya7;
    bf16x8 Yb0, Yb1, Yb2, Yb3, Yb4, Yb5, Yb6, Yb7;

    // prologue: stage tiles 0,1; wait tile 0 (stage(1) stays in flight);
    // issue F(0) reads into X.
    stageA(xbf, brow, 0, As0, tid); stageB(Wt, bcol, 0, Bs0, tid);
    stageA(xbf, brow, 1, As1, tid); stageB(Wt, bcol, 1, Bs1, tid);
    SB();
    VMW(6);
    BAR();
    ISSUE_DS(X, As0, Bs0);
    SB();

    //    next-set  rd-slot    stage-u  dst      cur-set
    TILE(Y, As1, Bs1,  2, As2, Bs2, X, true);   // u=0
    TILE(X, As2, Bs2,  3, As0, Bs0, Y, true);   // u=1
    TILE(Y, As0, Bs0,  4, As1, Bs1, X, true);   // u=2
    TILE(X, As1, Bs1,  5, As2, Bs2, Y, true);   // u=3
    TILE(Y, As2, Bs2,  6, As0, Bs0, X, true);   // u=4
    TILE(X, As0, Bs0,  7, As1, Bs1, Y, true);   // u=5
    TILE(Y, As1, Bs1,  8, As2, Bs2, X, true);   // u=6
    TILE(X, As2, Bs2,  9, As0, Bs0, Y, true);   // u=7
    TILE(Y, As0, Bs0, 10, As1, Bs1, X, true);   // u=8
    TILE(X, As1, Bs1, 11, As2, Bs2, Y, true);   // u=9
    TILE(Y, As2, Bs2, 12, As0, Bs0, X, true);   // u=10
    TILE(X, As0, Bs0, 13, As1, Bs1, Y, true);   // u=11
    TILE(Y, As1, Bs1, 14, As2, Bs2, X, true);   // u=12
    TILE(X, As2, Bs2, 15, As0, Bs0, Y, true);   // u=13
    TILE(Y, As0, Bs0,  0, As0, Bs0, X, false);  // u=14: rd F(15), no stage
    // u=15: nothing to read or stage; drain Y's reads, compute.
    LGW(0);
    MFMA_SET(Y);
    SB();

    // ---- epilogue: per-expert bias + relu, sum, store f32 (r9-verified)
    int i0, i1; top2(logits, i0, i1);
    #pragma unroll
    for (int n16 = 0; n16 < 2; ++n16) {
        const int col = bcol + cgrp * 32 + n16 * 16 + l15;
        const float bb0 = bs[i0 * D + col];
        const float bb1 = bs[i1 * D + col];
        #pragma unroll
        for (int m = 0; m < 4; ++m) {
            const int rbase = brow + rgrp * 64 + m * 16 + lq * 4;
            #pragma unroll
            for (int i = 0; i < 4; ++i) {
                float v0 = acc[0][m][n16][i] + bb0; v0 = v0 > 0.f ? v0 : 0.f;
                float v1 = acc[1][m][n16][i] + bb1; v1 = v1 > 0.f ? v1 : 0.f;
                out[(size_t)(rbase + i) * D + col] = v0 + v1;
            }
        }
    }
}

extern "C" void kernel_launch(void* const* d_in, const int* in_sizes, int n_in,
                              void* d_out, int out_size, void* d_ws, size_t ws_size,
                              hipStream_t stream) {
    const float* x      = (const float*)d_in[0];
    const float* logits = (const float*)d_in[1];
    const float* Ws     = (const float*)d_in[2];
    const float* bs     = (const float*)d_in[3];
    float* out = (float*)d_out;

    char* ws = (char*)d_ws;
    ushort_t* xbf = (ushort_t*)ws;                                   // 16 MB
    ushort_t* Wt  = (ushort_t*)(ws + (size_t)B_ROWS * D * 2);        //  4 MB

    prep_kernel<<<4096 + 2048, 256, 0, stream>>>(x, Ws, logits, xbf, Wt);
    gemm_dual<<<512, 512, 0, stream>>>(xbf, Wt, bs, logits, out);
}

// Round 19
// 47.190 us; speedup vs baseline: 1.2387x; 1.0396x over previous
//
#include <hip/hip_runtime.h>
#include <hip/hip_bf16.h>

#define NUM_OPS 8
#define D 1024
#define B_ROWS 8192

typedef unsigned short ushort_t;
typedef __attribute__((ext_vector_type(8))) short bf16x8;
typedef __attribute__((ext_vector_type(4))) float f32x4;
typedef __attribute__((ext_vector_type(4))) float float4v;
typedef __attribute__((ext_vector_type(8))) unsigned short ushort8;

__device__ __forceinline__ unsigned short f2bf(float f) {
    union { float f; unsigned int u; } v; v.f = f;
    unsigned int u = v.u;
    unsigned int lsb = (u >> 16) & 1u;
    u += 0x7fffu + lsb;   // round-to-nearest-even
    return (unsigned short)(u >> 16);
}

__device__ __forceinline__ void load_lds16(const void* g, void* l) {
    __builtin_amdgcn_global_load_lds(
        (const __attribute__((address_space(1))) void*)g,
        (__attribute__((address_space(3))) void*)l,
        16, 0, 0);
}

// deterministic top-2 (matches jax top_k tie-breaking: earliest index wins)
__device__ __forceinline__ void top2(const float* __restrict__ logits, int& i0, int& i1) {
    float best = -__builtin_inff(); i0 = 0;
    for (int i = 0; i < NUM_OPS; ++i) { float v = logits[i]; if (v > best) { best = v; i0 = i; } }
    float best2 = -__builtin_inff(); i1 = 0;
    for (int i = 0; i < NUM_OPS; ++i) {
        if (i == i0) continue;
        float v = logits[i]; if (v > best2) { best2 = v; i1 = i; }
    }
}

// -------- merged prep: x->bf16 linear (blocks 0..4095), W gather-transpose --
__global__ void prep_kernel(const float* __restrict__ x,
                            const float* __restrict__ Ws,
                            const float* __restrict__ logits,
                            ushort_t* __restrict__ xbf,
                            ushort_t* __restrict__ Wt) {
    __shared__ float t[32][33];
    const int bid = blockIdx.x;
    const int tid = threadIdx.x;
    if (bid < 4096) {
        // convert_x (r9-verified)
        int i = (bid * 256 + tid) * 8;
        float4v v0 = *(const float4v*)(x + i);
        float4v v1 = *(const float4v*)(x + i + 4);
        ushort8 o;
        o[0] = f2bf(v0[0]); o[1] = f2bf(v0[1]); o[2] = f2bf(v0[2]); o[3] = f2bf(v0[3]);
        o[4] = f2bf(v1[0]); o[5] = f2bf(v1[1]); o[6] = f2bf(v1[2]); o[7] = f2bf(v1[3]);
        *(ushort8*)(xbf + i) = o;
    } else {
        // gather_transpose_W (r9-verified): Wt[e][n*D+k] = bf16(W_sel[k*D+n])
        int i0, i1; top2(logits, i0, i1);
        const int b  = bid - 4096;
        const int e    = b >> 10;
        const int tile = b & 1023;
        const int td = (tile >> 5) << 5;
        const int te = (tile & 31) << 5;
        const int tx = tid & 31, ty = tid >> 5;
        const float* W = Ws + (size_t)(e ? i1 : i0) * D * D;
        for (int r = 0; r < 4; ++r)
            t[ty + 8 * r][tx] = W[(size_t)(td + ty + 8 * r) * D + te + tx];
        __syncthreads();
        ushort_t* o = Wt + (size_t)e * D * D;
        for (int r = 0; r < 4; ++r)
            o[(size_t)(te + ty + 8 * r) * D + td + tx] = f2bf(t[tx][ty + 8 * r]);
    }
}

// -------- staging (r9-verified): linear LDS dest, inverse-swizzled source ---
// LDS row = 128B; byte (r*128+c') holds global col-byte (c' ^ ((r&7)<<4)).
__device__ __forceinline__ void stageA(const ushort_t* __restrict__ xbf, int brow,
                                       int u, ushort_t* dst, int tid) {
    #pragma unroll
    for (int q = 0; q < 4; ++q) {                       // 256 rows x 128B = 32KB
        const int c   = q * 512 + tid;
        const int rr  = c >> 3;
        const int gcb = ((c & 7) * 16) ^ ((rr & 7) << 4);
        load_lds16(xbf + (size_t)(brow + rr) * D + u * 64 + (gcb >> 1), dst + c * 8);
    }
}
__device__ __forceinline__ void stageB(const ushort_t* __restrict__ Wt, int bcol,
                                       int u, ushort_t* dst, int tid) {
    #pragma unroll
    for (int q = 0; q < 2; ++q) {                       // 2e x 64 rows x 128B = 16KB
        const int c   = q * 512 + tid;
        const int e   = c >> 9, cc = c & 511;
        const int n   = cc >> 3;
        const int gcb = ((cc & 7) * 16) ^ ((n & 7) << 4);
        load_lds16(Wt + (size_t)e * D * D + (size_t)(bcol + n) * D + u * 64 + (gcb >> 1),
                   dst + c * 8);
    }
}

#define SB()    __builtin_amdgcn_sched_barrier(0)
#define PRIO1() __builtin_amdgcn_s_setprio(1)
#define PRIO0() __builtin_amdgcn_s_setprio(0)
#define VMW(N)  do { asm volatile("s_waitcnt vmcnt(" #N ")" ::: "memory"); SB(); } while (0)
#define LGW(N)  do { asm volatile("s_waitcnt lgkmcnt(" #N ")" ::: "memory"); SB(); } while (0)
#define BAR()   do { __builtin_amdgcn_s_barrier(); SB(); } while (0)

// inline-asm LDS read: allocator cannot collapse these; regs stay live.
#define DSR(dst, addr, imm)                                                    \
    asm volatile("ds_read_b128 %0, %1 offset:" #imm : "=v"(dst) : "v"(addr))

// issue one tile's 16 fragment ds_reads into named set P from slots SA/SBB.
#define ISSUE_DS(P, SA, SBB)                                                   \
    do {                                                                       \
        unsigned aA0 = (unsigned)(size_t)(SA) + aro + x0;                      \
        unsigned aA1 = (unsigned)(size_t)(SA) + aro + x1;                      \
        unsigned aB0 = (unsigned)(size_t)(SBB) + bro + x0;                     \
        unsigned aB1 = (unsigned)(size_t)(SBB) + bro + x1;                     \
        DSR(P##a0, aA0, 0);    DSR(P##a1, aA0, 2048);                          \
        DSR(P##a2, aA0, 4096); DSR(P##a3, aA0, 6144);                          \
        DSR(P##a4, aA1, 0);    DSR(P##a5, aA1, 2048);                          \
        DSR(P##a6, aA1, 4096); DSR(P##a7, aA1, 6144);                          \
        DSR(P##b0, aB0, 0);    DSR(P##b1, aB0, 2048);                          \
        DSR(P##b4, aB0, 8192); DSR(P##b5, aB0, 10240);                         \
        DSR(P##b2, aB1, 0);    DSR(P##b3, aB1, 2048);                          \
        DSR(P##b6, aB1, 8192); DSR(P##b7, aB1, 10240);                         \
    } while (0)

#define MF(a, b, c) __builtin_amdgcn_mfma_f32_16x16x32_bf16(a, b, c, 0, 0, 0)
#define Q(P, A, B, E, M, N) acc[E][M][N] = MF(P##A, P##B, acc[E][M][N])

// 32 MFMA on set P. a index = kk*4+m ; b index = e*4 + kk*2 + n16 (r8-verified)
#define MFMA_SET(P)                                                            \
    do {                                                                       \
        PRIO1();                                                               \
        Q(P,a0,b0,0,0,0); Q(P,a0,b1,0,0,1); Q(P,a0,b4,1,0,0); Q(P,a0,b5,1,0,1);\
        Q(P,a1,b0,0,1,0); Q(P,a1,b1,0,1,1); Q(P,a1,b4,1,1,0); Q(P,a1,b5,1,1,1);\
        Q(P,a2,b0,0,2,0); Q(P,a2,b1,0,2,1); Q(P,a2,b4,1,2,0); Q(P,a2,b5,1,2,1);\
        Q(P,a3,b0,0,3,0); Q(P,a3,b1,0,3,1); Q(P,a3,b4,1,3,0); Q(P,a3,b5,1,3,1);\
        Q(P,a4,b2,0,0,0); Q(P,a4,b3,0,0,1); Q(P,a4,b6,1,0,0); Q(P,a4,b7,1,0,1);\
        Q(P,a5,b2,0,1,0); Q(P,a5,b3,0,1,1); Q(P,a5,b6,1,1,0); Q(P,a5,b7,1,1,1);\
        Q(P,a6,b2,0,2,0); Q(P,a6,b3,0,2,1); Q(P,a6,b6,1,2,0); Q(P,a6,b7,1,2,1);\
        Q(P,a7,b2,0,3,0); Q(P,a7,b3,0,3,1); Q(P,a7,b6,1,3,0); Q(P,a7,b7,1,3,1);\
        PRIO0();                                                               \
    } while (0)

// one K-tile u (steady state), deep-staged:
//   VMW(6): drains stage(u+1) (issued TWO tiles ago -> free); stage(u+2)'s
//     6 loads stay in flight -- staging never drains to zero (Little's law).
//   BARRIER: slot[(u+1)%3] visible to all waves.
//   ISSUE_DS F(u+1) (16 asm ds_read; fly under MFMA(u))
//   LGW(15): drains F(u)'s 16 reads (issued last tile) -> slot[u%3]'s old
//     content is dead for ALL consumers of this tile.
//   stage(u+3) into slot[(u+3)%3] == slot[u%3] -- WAR-safe: this wave's F(u)
//     reads drained above; other waves' F(u) reads were issued before this
//     tile's barrier and their slot reads complete under queue order long
//     before these global loads return data.
//   MFMA_SET(F(u))
#define TILE(SETN, SA, SBB, SU, DA, DB, SETC, DOSTG, VN)                       \
    do {                                                                       \
        VMW(VN);                                                               \
        BAR();                                                                 \
        ISSUE_DS(SETN, SA, SBB);                                               \
        SB();                                                                  \
        LGW(15);                                                               \
        if (DOSTG) { stageA(xbf, brow, (SU), DA, tid);                         \
                     stageB(Wt,  bcol, (SU), DB, tid); }                       \
        SB();                                                                  \
        MFMA_SET(SETC);                                                        \
        SB();                                                                  \
    } while (0)

// -------- fused dual-expert GEMM: asm LDS pipeline + never-drained staging --
// r18 base (best known). ONE change: staging depth 2->3 tiles with counted
// VMW(6) at tile top (was VMW(0)) -- in-flight staging bytes go from a
// 48KB->0 sawtooth to a steady 48-96KB, ~3x average, doubling Little's-law
// delivery from the ~31-44 B/cyc/CU all drain-to-zero schedules measured.
__global__ __launch_bounds__(512, 2)
void gemm_dual(const ushort_t* __restrict__ xbf, const ushort_t* __restrict__ Wt,
               const float* __restrict__ bs, const float* __restrict__ logits,
               float* __restrict__ out) {
    __shared__ __align__(16) ushort_t As0[256 * 64], As1[256 * 64], As2[256 * 64];
    __shared__ __align__(16) ushort_t Bs0[2 * 64 * 64], Bs1[2 * 64 * 64], Bs2[2 * 64 * 64];

    const int tid  = threadIdx.x;
    const int wv   = tid >> 6;
    const int lane = tid & 63;
    const int rgrp = wv >> 1, cgrp = wv & 1;
    const int l15  = lane & 15, lq = lane >> 4;
    const int swz  = (l15 & 7) << 4;
    const int x0   = (lq * 16) ^ swz;
    const int x1   = (64 + lq * 16) ^ swz;
    const unsigned aro = (unsigned)((rgrp * 64 + l15) * 128);
    const unsigned bro = (unsigned)((cgrp * 32 + l15) * 128);

    const int bid  = blockIdx.x;
    const int brow = (bid & 31) * 256;
    const int bcol = (bid >> 5) * 64;

    f32x4 acc[2][4][2] = {};

    bf16x8 Xa0, Xa1, Xa2, Xa3, Xa4, Xa5, Xa6, Xa7;
    bf16x8 Xb0, Xb1, Xb2, Xb3, Xb4, Xb5, Xb6, Xb7;
    bf16x8 Ya0, Ya1, Ya2, Ya3, Ya4, Ya5, Ya6, Ya7;
    bf16x8 Yb0, Yb1, Yb2, Yb3, Yb4, Yb5, Yb6, Yb7;

    // prologue: stage tiles 0,1,2 (18 loads); wait stage(0) only (12 stay in
    // flight); issue F(0) reads into X.
    stageA(xbf, brow, 0, As0, tid); stageB(Wt, bcol, 0, Bs0, tid);
    stageA(xbf, brow, 1, As1, tid); stageB(Wt, bcol, 1, Bs1, tid);
    stageA(xbf, brow, 2, As2, tid); stageB(Wt, bcol, 2, Bs2, tid);
    SB();
    VMW(12);
    BAR();
    ISSUE_DS(X, As0, Bs0);
    SB();

    //    next-set rd-slot    stage-u  dst      cur  stg  vmn
    TILE(Y, As1, Bs1,  3, As0, Bs0, X, true,  6);   // u=0
    TILE(X, As2, Bs2,  4, As1, Bs1, Y, true,  6);   // u=1
    TILE(Y, As0, Bs0,  5, As2, Bs2, X, true,  6);   // u=2
    TILE(X, As1, Bs1,  6, As0, Bs0, Y, true,  6);   // u=3
    TILE(Y, As2, Bs2,  7, As1, Bs1, X, true,  6);   // u=4
    TILE(X, As0, Bs0,  8, As2, Bs2, Y, true,  6);   // u=5
    TILE(Y, As1, Bs1,  9, As0, Bs0, X, true,  6);   // u=6
    TILE(X, As2, Bs2, 10, As1, Bs1, Y, true,  6);   // u=7
    TILE(Y, As0, Bs0, 11, As2, Bs2, X, true,  6);   // u=8
    TILE(X, As1, Bs1, 12, As0, Bs0, Y, true,  6);   // u=9
    TILE(Y, As2, Bs2, 13, As1, Bs1, X, true,  6);   // u=10
    TILE(X, As0, Bs0, 14, As2, Bs2, Y, true,  6);   // u=11
    TILE(Y, As1, Bs1, 15, As0, Bs0, X, true,  6);   // u=12
    TILE(X, As2, Bs2,  0, As0, Bs0, Y, false, 6);   // u=13 (no stage)
    TILE(Y, As0, Bs0,  0, As0, Bs0, X, false, 0);   // u=14 (drain stage(15))
    // u=15: drain Y's reads, compute.
    LGW(0);
    MFMA_SET(Y);
    SB();

    // ---- epilogue: per-expert bias + relu, sum, store f32 (r9-verified)
    int i0, i1; top2(logits, i0, i1);
    #pragma unroll
    for (int n16 = 0; n16 < 2; ++n16) {
        const int col = bcol + cgrp * 32 + n16 * 16 + l15;
        const float bb0 = bs[i0 * D + col];
        const float bb1 = bs[i1 * D + col];
        #pragma unroll
        for (int m = 0; m < 4; ++m) {
            const int rbase = brow + rgrp * 64 + m * 16 + lq * 4;
            #pragma unroll
            for (int i = 0; i < 4; ++i) {
                float v0 = acc[0][m][n16][i] + bb0; v0 = v0 > 0.f ? v0 : 0.f;
                float v1 = acc[1][m][n16][i] + bb1; v1 = v1 > 0.f ? v1 : 0.f;
                out[(size_t)(rbase + i) * D + col] = v0 + v1;
            }
        }
    }
}

extern "C" void kernel_launch(void* const* d_in, const int* in_sizes, int n_in,
                              void* d_out, int out_size, void* d_ws, size_t ws_size,
                              hipStream_t stream) {
    const float* x      = (const float*)d_in[0];
    const float* logits = (const float*)d_in[1];
    const float* Ws     = (const float*)d_in[2];
    const float* bs     = (const float*)d_in[3];
    float* out = (float*)d_out;

    char* ws = (char*)d_ws;
    ushort_t* xbf = (ushort_t*)ws;                                   // 16 MB
    ushort_t* Wt  = (ushort_t*)(ws + (size_t)B_ROWS * D * 2);        //  4 MB

    prep_kernel<<<4096 + 2048, 256, 0, stream>>>(x, Ws, logits, xbf, Wt);
    gemm_dual<<<512, 512, 0, stream>>>(xbf, Wt, bs, logits, out);
}